// Round 7
// baseline (135.020 us; speedup 1.0000x reference)
//
#include <hip/hip_runtime.h>
#include <hip/hip_bf16.h>
#include <stdint.h>

typedef __bf16 bf16x8 __attribute__((ext_vector_type(8)));
typedef float  f32x4  __attribute__((ext_vector_type(4)));

#define NROWS   8192
#define DIMK    128
#define NGROUPS 2048
#define RECON_N 6422528
#define RECON_N4 (RECON_N / 4)             // 1605632 float4s
#define RECON_BLOCKS 1024
#define GROUP_BLOCKS (NGROUPS / 4)         // 512

// workspace layout (floats)
#define WS_SP     0                        // Sp[8][8192]
#define WS_G      (WS_SP + 8 * NROWS)      // 65536
#define WS_E      (WS_G + NROWS)           // 73728
#define WS_RPART  (WS_E + NROWS)           // 81920, 1024 entries
#define WS_DPART  (WS_RPART + RECON_BLOCKS)// 82944, 512 entries
#define WS_PB     (WS_DPART + GROUP_BLOCKS)// 83456 floats = byte 333824 (16B aligned)

__device__ __forceinline__ void async16(const void* g, void* l) {
    __builtin_amdgcn_global_load_lds(
        (const __attribute__((address_space(1))) void*)g,
        (__attribute__((address_space(3))) void*)l, 16, 0, 0);
}

__device__ __forceinline__ unsigned short f2bf(float f) {
    union { __hip_bfloat16 h; unsigned short u; } v;
    v.h = __float2bfloat16(f);
    return v.u;
}

// -------- convert projections fp32 -> bf16 (RNE) --------
__global__ __launch_bounds__(256) void convert_kernel(const float4* __restrict__ P,
                                                      uint2* __restrict__ out) {
    int idx = blockIdx.x * 256 + threadIdx.x;   // 262144 threads
    float4 a = P[idx];
    uint2 r;
    r.x = (uint32_t)f2bf(a.x) | ((uint32_t)f2bf(a.y) << 16);
    r.y = (uint32_t)f2bf(a.z) | ((uint32_t)f2bf(a.w) << 16);
    out[idx] = r;
}

// -------- recon partials: float4 grid-stride, per-block plain store --------
__global__ __launch_bounds__(256) void recon_kernel(const float4* __restrict__ x,
                                                    const float4* __restrict__ y,
                                                    float* __restrict__ rpart) {
    __shared__ float red[4];
    float s = 0.f;
    for (int i = blockIdx.x * 256 + threadIdx.x; i < RECON_N4; i += 256 * RECON_BLOCKS) {
        float4 a = x[i], b = y[i];
        float d0 = a.x - b.x, d1 = a.y - b.y, d2 = a.z - b.z, d3 = a.w - b.w;
        s += d0 * d0 + d1 * d1 + d2 * d2 + d3 * d3;
    }
#pragma unroll
    for (int m = 1; m < 64; m <<= 1) s += __shfl_xor(s, m, 64);
    int wave = threadIdx.x >> 6, lane = threadIdx.x & 63;
    if (lane == 0) red[wave] = s;
    __syncthreads();
    if (threadIdx.x == 0)
        rpart[blockIdx.x] = red[0] + red[1] + red[2] + red[3];
}

// -------- per-group: G_i, E_i, dist partial. One wave per group, fp32 --------
__global__ __launch_bounds__(256) void group_kernel(const float* __restrict__ P,
                                                    float* __restrict__ G,
                                                    float* __restrict__ E,
                                                    float* __restrict__ dpart) {
    __shared__ float dred[4];
    int wave = threadIdx.x >> 6, lane = threadIdx.x & 63;
    int g = blockIdx.x * 4 + wave;
    const float* base = P + (size_t)g * 4 * DIMK;
    float v[4][2];
#pragma unroll
    for (int r = 0; r < 4; ++r) {
        v[r][0] = base[r * DIMK + lane];
        v[r][1] = base[r * DIMK + 64 + lane];
    }
    float d[4][4];
#pragma unroll
    for (int r = 0; r < 4; ++r)
#pragma unroll
        for (int s = r; s < 4; ++s) {
            float p = v[r][0] * v[s][0] + v[r][1] * v[s][1];
#pragma unroll
            for (int m = 1; m < 64; m <<= 1) p += __shfl_xor(p, m, 64);
            d[r][s] = p; d[s][r] = p;
        }
    if (lane == 0) {
        float distp = 0.f;
#pragma unroll
        for (int r = 0; r < 4; ++r)
#pragma unroll
            for (int s = r + 1; s < 4; ++s)
                distp += d[r][r] + d[s][s] - 2.f * d[r][s];
        dred[wave] = distp;
#pragma unroll
        for (int r = 0; r < 4; ++r) {
            float Gs = 0.f, Es = 0.f;
#pragma unroll
            for (int s = 0; s < 4; ++s) {
                float sim = d[r][s] * 10.0f;
                float e = __expf(sim);
                Gs += e;
                if (sim == 1.0f) Es += e;
            }
            G[g * 4 + r] = Gs;
            E[g * 4 + r] = Es;
        }
    }
    __syncthreads();
    if (threadIdx.x == 0)
        dpart[blockIdx.x] = dred[0] + dred[1] + dred[2] + dred[3];
}

// -------- main: Sp[by][i] = sum_{j in chunk by} exp(P_i . P_j * 10) --------
// grid: (64 row-tiles, 8 col-chunks). Block 256 = 4 waves (2x2 of 64x64).
// The wc=0/wc=1 waves cover different column halves of the same rows;
// combine through sred[] before one coalesced store per row.
__global__ __launch_bounds__(256, 2) void sim_kernel(const unsigned short* __restrict__ P,
                                                     float* __restrict__ Sp) {
    __shared__ unsigned short tile[128 * 128];
    __shared__ float sred[2][2][64];   // [wc][wr][row-in-64]
    const int wave = threadIdx.x >> 6, lane = threadIdx.x & 63;
    const int wr = wave >> 1, wc = wave & 1;
    const int rowBase = blockIdx.x * 128;
    const int colBase = blockIdx.y * 1024;

    {
        const char* g = (const char*)(P + (size_t)rowBase * DIMK);
#pragma unroll
        for (int i = 0; i < 8; ++i) {
            int seg = i * 4 + wave;
            async16(g + seg * 1024 + lane * 16, (char*)tile + seg * 1024);
        }
    }
    __syncthreads();

    // preload A fragments: A[m][k], m = lane&15, k = (lane>>4)*8 + j
    bf16x8 Af[4][4];
    {
        int m = lane & 15, kq = lane >> 4;
#pragma unroll
        for (int i = 0; i < 4; ++i) {
            const unsigned short* rowp = tile + (wr * 64 + i * 16 + m) * 128 + kq * 8;
#pragma unroll
            for (int kk = 0; kk < 4; ++kk)
                Af[i][kk] = *(const bf16x8*)(rowp + kk * 32);
        }
    }
    __syncthreads();

    float rowAcc[4][4];
#pragma unroll
    for (int i = 0; i < 4; ++i)
#pragma unroll
        for (int r = 0; r < 4; ++r) rowAcc[i][r] = 0.f;

    for (int t = 0; t < 8; ++t) {
        {
            const char* g = (const char*)(P + (size_t)(colBase + t * 128) * DIMK);
#pragma unroll
            for (int i = 0; i < 8; ++i) {
                int seg = i * 4 + wave;
                async16(g + seg * 1024 + lane * 16, (char*)tile + seg * 1024);
            }
        }
        __syncthreads();

        f32x4 acc[4][4];
#pragma unroll
        for (int i = 0; i < 4; ++i)
#pragma unroll
            for (int j = 0; j < 4; ++j) acc[i][j] = (f32x4){0.f, 0.f, 0.f, 0.f};

        int n = lane & 15, kq = lane >> 4;
#pragma unroll
        for (int kk = 0; kk < 4; ++kk) {
            bf16x8 Bf[4];
#pragma unroll
            for (int j = 0; j < 4; ++j)
                Bf[j] = *(const bf16x8*)(tile + (wc * 64 + j * 16 + n) * 128 + kq * 8 + kk * 32);
#pragma unroll
            for (int i = 0; i < 4; ++i)
#pragma unroll
                for (int j = 0; j < 4; ++j)
                    acc[i][j] = __builtin_amdgcn_mfma_f32_16x16x32_bf16(Af[i][kk], Bf[j], acc[i][j], 0, 0, 0);
        }
#pragma unroll
        for (int i = 0; i < 4; ++i)
#pragma unroll
            for (int j = 0; j < 4; ++j)
#pragma unroll
                for (int r = 0; r < 4; ++r)
                    rowAcc[i][r] += __expf(acc[i][j][r] * 10.0f);
        __syncthreads();
    }

#pragma unroll
    for (int i = 0; i < 4; ++i)
#pragma unroll
        for (int r = 0; r < 4; ++r) {
            float sv = rowAcc[i][r];
            sv += __shfl_xor(sv, 1, 64);
            sv += __shfl_xor(sv, 2, 64);
            sv += __shfl_xor(sv, 4, 64);
            sv += __shfl_xor(sv, 8, 64);
            rowAcc[i][r] = sv;
        }
    if ((lane & 15) == 0) {
        int c = lane >> 4;
#pragma unroll
        for (int i = 0; i < 4; ++i)
#pragma unroll
            for (int r = 0; r < 4; ++r)
                sred[wc][wr][i * 16 + c * 4 + r] = rowAcc[i][r];
    }
    __syncthreads();
    if (wc == 0) {
        float v = sred[0][wr][lane] + sred[1][wr][lane];
        Sp[(size_t)blockIdx.y * NROWS + rowBase + wr * 64 + lane] = v;
    }
}

// -------- finalize: sum partials, closs mean, combine. FP32 OUTPUTS. --------
__global__ __launch_bounds__(256) void finalize_kernel(const float* __restrict__ ws,
                                                       float* __restrict__ out) {
    const float* Sp    = ws + WS_SP;
    const float* G     = ws + WS_G;
    const float* E     = ws + WS_E;
    const float* rpart = ws + WS_RPART;
    const float* dpart = ws + WS_DPART;
    __shared__ float redc[4], redr[4], redd[4];

    float c = 0.f;
    for (int r = threadIdx.x; r < NROWS; r += 256) {
        float Sv = 0.f;
#pragma unroll
        for (int q = 0; q < 8; ++q) Sv += Sp[q * NROWS + r];
        c += __logf(Sv - E[r]) - __logf(G[r] - E[r]);
    }
    float rs = 0.f;
    for (int i = threadIdx.x; i < RECON_BLOCKS; i += 256) rs += rpart[i];
    float ds = 0.f;
    for (int i = threadIdx.x; i < GROUP_BLOCKS; i += 256) ds += dpart[i];

#pragma unroll
    for (int m = 1; m < 64; m <<= 1) {
        c  += __shfl_xor(c,  m, 64);
        rs += __shfl_xor(rs, m, 64);
        ds += __shfl_xor(ds, m, 64);
    }
    int wave = threadIdx.x >> 6, lane = threadIdx.x & 63;
    if (lane == 0) { redc[wave] = c; redr[wave] = rs; redd[wave] = ds; }
    __syncthreads();
    if (threadIdx.x == 0) {
        float closs = (redc[0] + redc[1] + redc[2] + redc[3]) / (float)NROWS;
        float recon = (redr[0] + redr[1] + redr[2] + redr[3]) / (float)RECON_N;
        float dist  = (redd[0] + redd[1] + redd[2] + redd[3]) / (float)(NGROUPS * 6 * DIMK);
        float loss  = recon + closs + dist;
        out[0] = loss;    // fp32 — the reference's output dtype
        out[1] = closs;
        out[2] = recon;
        out[3] = dist;
    }
}

extern "C" void kernel_launch(void* const* d_in, const int* in_sizes, int n_in,
                              void* d_out, int out_size, void* d_ws, size_t ws_size,
                              hipStream_t stream) {
    const float* P  = (const float*)d_in[0];    // projections 8192x128 fp32
    const float4* X = (const float4*)d_in[1];   // xrecon 8192x784 fp32
    const float4* Y = (const float4*)d_in[2];   // recon_label fp32
    float* out = (float*)d_out;                 // 4 fp32 scalars
    float* w = (float*)d_ws;
    unsigned short* Pb = (unsigned short*)(w + WS_PB);   // bf16 copy, 2 MB

    convert_kernel<<<NROWS * DIMK / 4 / 256, 256, 0, stream>>>((const float4*)P, (uint2*)Pb);
    recon_kernel<<<RECON_BLOCKS, 256, 0, stream>>>(X, Y, w + WS_RPART);
    group_kernel<<<GROUP_BLOCKS, 256, 0, stream>>>(P, w + WS_G, w + WS_E, w + WS_DPART);
    sim_kernel<<<dim3(64, 8), 256, 0, stream>>>(Pb, w + WS_SP);
    finalize_kernel<<<1, 256, 0, stream>>>(w, out);
}

// Round 8
// 126.215 us; speedup vs baseline: 1.0698x; 1.0698x over previous
//
#include <hip/hip_runtime.h>
#include <hip/hip_bf16.h>
#include <stdint.h>

typedef __bf16 bf16x8 __attribute__((ext_vector_type(8)));
typedef float  f32x4  __attribute__((ext_vector_type(4)));

#define NROWS   8192
#define DIMK    128
#define NGROUPS 2048
#define RECON_N 6422528
#define RECON_N4 (RECON_N / 4)       // 1605632 float4s = 1568 * 1024
#define SIM_BLOCKS   512             // 64 row-tiles x 8 col-chunks
#define RECON_BLOCKS 1568            // x 256 thr x 4 float4 = 1605632
#define GROUP_BLOCKS (NGROUPS / 4)   // 512
#define FUSED_BLOCKS (SIM_BLOCKS + RECON_BLOCKS + GROUP_BLOCKS)  // 2592
#define CLOSS_BLOCKS 32

// exp(10*x) = exp2(x * 10/ln2)
#define LOG2E10 14.4269504088896341f

// workspace layout (float offsets)
#define WS_SP     0                         // Sp[8][8192]
#define WS_G      65536                     // 8192
#define WS_E      73728                     // 8192
#define WS_RPART  81920                     // 1568
#define WS_DPART  83488                     // 512
#define WS_CPART  84000                     // 32
#define WS_PB     84032                     // byte 336128, 16B aligned; bf16 copy 2MB

__device__ __forceinline__ unsigned short f2bf(float f) {
    union { __hip_bfloat16 h; unsigned short u; } v;
    v.h = __float2bfloat16(f);
    return v.u;
}

// -------- k1: convert projections fp32 -> bf16 (RNE) --------
__global__ __launch_bounds__(256) void convert_kernel(const float4* __restrict__ P,
                                                      uint2* __restrict__ out) {
    int idx = blockIdx.x * 256 + threadIdx.x;   // 262144 threads
    float4 a = P[idx];
    uint2 r;
    r.x = (uint32_t)f2bf(a.x) | ((uint32_t)f2bf(a.y) << 16);
    r.y = (uint32_t)f2bf(a.z) | ((uint32_t)f2bf(a.w) << 16);
    out[idx] = r;
}

// -------- k2: fused sim (barrier-free, global-frag) + recon + group --------
// blocks [0,512): sim. [512,2080): recon. [2080,2592): group.
__global__ __launch_bounds__(256, 2) void fused_kernel(
        const unsigned short* __restrict__ Pb,   // bf16 projections
        const float* __restrict__ Pf,            // fp32 projections
        const float4* __restrict__ X,
        const float4* __restrict__ Y,
        float* __restrict__ ws) {
    const int bx = blockIdx.x;
    const int wave = threadIdx.x >> 6, lane = threadIdx.x & 63;

    if (bx < SIM_BLOCKS) {
        // ---------------- sim: Sp[by][row] = sum_j exp(P_row . P_j * 10) ----
        float* Sp = ws + WS_SP;
        __shared__ float sred[2][2][64];      // [wc][wr][row-in-64]
        const int wr = wave >> 1, wc = wave & 1;
        const int rowBase = (bx >> 3) * 128;
        const int colBase = (bx & 7) * 1024;
        const int m = lane & 15, kq = lane >> 4;

        // A fragments straight from global (L2-resident, 2 MB total)
        bf16x8 Af[4][4];
#pragma unroll
        for (int i = 0; i < 4; ++i) {
            const unsigned short* rowp =
                Pb + (size_t)(rowBase + wr * 64 + i * 16 + m) * DIMK + kq * 8;
#pragma unroll
            for (int kk = 0; kk < 4; ++kk)
                Af[i][kk] = *(const bf16x8*)(rowp + kk * 32);
        }

        float rowAcc[4][4];
#pragma unroll
        for (int i = 0; i < 4; ++i)
#pragma unroll
            for (int r = 0; r < 4; ++r) rowAcc[i][r] = 0.f;

        for (int t = 0; t < 8; ++t) {
            const unsigned short* bbase =
                Pb + (size_t)(colBase + t * 128 + wc * 64) * DIMK;
#pragma unroll
            for (int j = 0; j < 4; ++j) {
                const unsigned short* bp = bbase + (j * 16 + m) * DIMK + kq * 8;
                bf16x8 Bf[4];
#pragma unroll
                for (int kk = 0; kk < 4; ++kk)
                    Bf[kk] = *(const bf16x8*)(bp + kk * 32);
                f32x4 acc[4];
#pragma unroll
                for (int i = 0; i < 4; ++i) acc[i] = (f32x4){0.f, 0.f, 0.f, 0.f};
#pragma unroll
                for (int kk = 0; kk < 4; ++kk)
#pragma unroll
                    for (int i = 0; i < 4; ++i)
                        acc[i] = __builtin_amdgcn_mfma_f32_16x16x32_bf16(
                            Af[i][kk], Bf[kk], acc[i], 0, 0, 0);
#pragma unroll
                for (int i = 0; i < 4; ++i)
#pragma unroll
                    for (int r = 0; r < 4; ++r)
                        rowAcc[i][r] += exp2f(acc[i][r] * LOG2E10);
            }
        }

        // reduce over the 16 lanes sharing a row (low 4 lane bits = col-in-16)
#pragma unroll
        for (int i = 0; i < 4; ++i)
#pragma unroll
            for (int r = 0; r < 4; ++r) {
                float sv = rowAcc[i][r];
                sv += __shfl_xor(sv, 1, 64);
                sv += __shfl_xor(sv, 2, 64);
                sv += __shfl_xor(sv, 4, 64);
                sv += __shfl_xor(sv, 8, 64);
                rowAcc[i][r] = sv;
            }
        if ((lane & 15) == 0) {
            int c = lane >> 4;
#pragma unroll
            for (int i = 0; i < 4; ++i)
#pragma unroll
                for (int r = 0; r < 4; ++r)
                    sred[wc][wr][i * 16 + c * 4 + r] = rowAcc[i][r];
        }
        __syncthreads();
        if (wc == 0) {
            float v = sred[0][wr][lane] + sred[1][wr][lane];
            Sp[(size_t)(bx & 7) * NROWS + rowBase + wr * 64 + lane] = v;
        }
    } else if (bx < SIM_BLOCKS + RECON_BLOCKS) {
        // ---------------- recon: 4 independent float4s per thread ----------
        __shared__ float red[4];
        int rb = bx - SIM_BLOCKS;
        int base = rb * 1024 + threadIdx.x;
        float4 a0 = X[base], b0 = Y[base];
        float4 a1 = X[base + 256], b1 = Y[base + 256];
        float4 a2 = X[base + 512], b2 = Y[base + 512];
        float4 a3 = X[base + 768], b3 = Y[base + 768];
        float s = 0.f;
        float d;
        d = a0.x - b0.x; s += d * d;  d = a0.y - b0.y; s += d * d;
        d = a0.z - b0.z; s += d * d;  d = a0.w - b0.w; s += d * d;
        d = a1.x - b1.x; s += d * d;  d = a1.y - b1.y; s += d * d;
        d = a1.z - b1.z; s += d * d;  d = a1.w - b1.w; s += d * d;
        d = a2.x - b2.x; s += d * d;  d = a2.y - b2.y; s += d * d;
        d = a2.z - b2.z; s += d * d;  d = a2.w - b2.w; s += d * d;
        d = a3.x - b3.x; s += d * d;  d = a3.y - b3.y; s += d * d;
        d = a3.z - b3.z; s += d * d;  d = a3.w - b3.w; s += d * d;
#pragma unroll
        for (int mm = 1; mm < 64; mm <<= 1) s += __shfl_xor(s, mm, 64);
        if (lane == 0) red[wave] = s;
        __syncthreads();
        if (threadIdx.x == 0)
            ws[WS_RPART + rb] = red[0] + red[1] + red[2] + red[3];
    } else {
        // ---------------- group: G_i, E_i, dist partial --------------------
        __shared__ float dred[4];
        float* G = ws + WS_G;
        float* E = ws + WS_E;
        int gb = bx - (SIM_BLOCKS + RECON_BLOCKS);
        int g = gb * 4 + wave;
        const float* base = Pf + (size_t)g * 4 * DIMK;
        float v[4][2];
#pragma unroll
        for (int r = 0; r < 4; ++r) {
            v[r][0] = base[r * DIMK + lane];
            v[r][1] = base[r * DIMK + 64 + lane];
        }
        float dmat[4][4];
#pragma unroll
        for (int r = 0; r < 4; ++r)
#pragma unroll
            for (int s2 = r; s2 < 4; ++s2) {
                float p = v[r][0] * v[s2][0] + v[r][1] * v[s2][1];
#pragma unroll
                for (int mm = 1; mm < 64; mm <<= 1) p += __shfl_xor(p, mm, 64);
                dmat[r][s2] = p; dmat[s2][r] = p;
            }
        if (lane == 0) {
            float distp = 0.f;
#pragma unroll
            for (int r = 0; r < 4; ++r)
#pragma unroll
                for (int s2 = r + 1; s2 < 4; ++s2)
                    distp += dmat[r][r] + dmat[s2][s2] - 2.f * dmat[r][s2];
            dred[wave] = distp;
#pragma unroll
            for (int r = 0; r < 4; ++r) {
                float Gs = 0.f, Es = 0.f;
#pragma unroll
                for (int s2 = 0; s2 < 4; ++s2) {
                    float sim = dmat[r][s2] * 10.0f;
                    float e = __expf(sim);
                    Gs += e;
                    if (sim == 1.0f) Es += e;
                }
                G[g * 4 + r] = Gs;
                E[g * 4 + r] = Es;
            }
        }
        __syncthreads();
        if (threadIdx.x == 0)
            ws[WS_DPART + gb] = dred[0] + dred[1] + dred[2] + dred[3];
    }
}

// -------- k3: closs partials, 32 blocks x 256 (one row per thread) --------
__global__ __launch_bounds__(256) void closs_kernel(const float* __restrict__ ws,
                                                    float* __restrict__ cpart) {
    __shared__ float red[4];
    const float* Sp = ws + WS_SP;
    const float* G  = ws + WS_G;
    const float* E  = ws + WS_E;
    int r = blockIdx.x * 256 + threadIdx.x;
    float Sv = 0.f;
#pragma unroll
    for (int q = 0; q < 8; ++q) Sv += Sp[q * NROWS + r];
    float c = __logf(Sv - E[r]) - __logf(G[r] - E[r]);
#pragma unroll
    for (int m = 1; m < 64; m <<= 1) c += __shfl_xor(c, m, 64);
    int wave = threadIdx.x >> 6, lane = threadIdx.x & 63;
    if (lane == 0) red[wave] = c;
    __syncthreads();
    if (threadIdx.x == 0)
        cpart[blockIdx.x] = red[0] + red[1] + red[2] + red[3];
}

// -------- k4: combine all partials, write 4 fp32 outputs --------
__global__ __launch_bounds__(256) void combine_kernel(const float* __restrict__ ws,
                                                      float* __restrict__ out) {
    __shared__ float redc[4], redr[4], redd[4];
    float cs = 0.f, rs = 0.f, ds = 0.f;
    for (int i = threadIdx.x; i < CLOSS_BLOCKS; i += 256) cs += ws[WS_CPART + i];
    for (int i = threadIdx.x; i < RECON_BLOCKS; i += 256) rs += ws[WS_RPART + i];
    for (int i = threadIdx.x; i < GROUP_BLOCKS; i += 256) ds += ws[WS_DPART + i];
#pragma unroll
    for (int m = 1; m < 64; m <<= 1) {
        cs += __shfl_xor(cs, m, 64);
        rs += __shfl_xor(rs, m, 64);
        ds += __shfl_xor(ds, m, 64);
    }
    int wave = threadIdx.x >> 6, lane = threadIdx.x & 63;
    if (lane == 0) { redc[wave] = cs; redr[wave] = rs; redd[wave] = ds; }
    __syncthreads();
    if (threadIdx.x == 0) {
        float closs = (redc[0] + redc[1] + redc[2] + redc[3]) / (float)NROWS;
        float recon = (redr[0] + redr[1] + redr[2] + redr[3]) / (float)RECON_N;
        float dist  = (redd[0] + redd[1] + redd[2] + redd[3]) / (float)(NGROUPS * 6 * DIMK);
        out[0] = recon + closs + dist;
        out[1] = closs;
        out[2] = recon;
        out[3] = dist;
    }
}

extern "C" void kernel_launch(void* const* d_in, const int* in_sizes, int n_in,
                              void* d_out, int out_size, void* d_ws, size_t ws_size,
                              hipStream_t stream) {
    const float* P  = (const float*)d_in[0];    // projections 8192x128 fp32
    const float4* X = (const float4*)d_in[1];   // xrecon 8192x784 fp32
    const float4* Y = (const float4*)d_in[2];   // recon_label fp32
    float* out = (float*)d_out;                 // 4 fp32 scalars
    float* w = (float*)d_ws;
    unsigned short* Pb = (unsigned short*)(w + WS_PB);

    convert_kernel<<<NROWS * DIMK / 4 / 256, 256, 0, stream>>>((const float4*)P, (uint2*)Pb);
    fused_kernel<<<FUSED_BLOCKS, 256, 0, stream>>>(Pb, P, X, Y, w);
    closs_kernel<<<CLOSS_BLOCKS, 256, 0, stream>>>(w, w + WS_CPART);
    combine_kernel<<<1, 256, 0, stream>>>(w, out);
}